// Round 4
// baseline (719.946 us; speedup 1.0000x reference)
//
#include <hip/hip_runtime.h>
#include <hip/hip_bf16.h>

// Nav_64939905516231 (VIN value iteration), MI355X gfx950.
// B=64,H=W=64,dim_h=150,n_hat=8,n_act=4,K=10. fp32 in/out, maze int32.
// Collapses: r = conv5x5(m,W_eff)+b_eff (150ch folded); q_t = q0 + conv5x5(v,w).
// 2 kernels: A = prep+r+q0 (per image-quarter); B = 10 fused steps + projection,
// with redundant halo compute (block owns 16 rows, computes shrinking region).
// R3 fix: rq_kernel phase-4 maze tile column index was off by +2 (cc+kx ->
// cc-2+kx); r was computed from a 2-col-shifted maze.

#define NHAT 8
#define DIMH 150
#define OWN 16

typedef float v2f __attribute__((ext_vector_type(2)));

// =============== Kernel A: prep + r + q0 =================
__global__ __launch_bounds__(256) void rq_kernel(
    const int* __restrict__ maze, const float* __restrict__ emb,
    const float* __restrict__ encode_w, const float* __restrict__ encode_b,
    const float* __restrict__ r_w, const float* __restrict__ q_w,
    float* __restrict__ q0g) {
  __shared__ float wpart[250];     // 5 chunks x 50 (i,k)
  __shared__ float bpart[152];
  __shared__ float weff[2][25];
  __shared__ float bsh;
  __shared__ float Ts[4][25];
  __shared__ v2f qw2[25][4];
  __shared__ unsigned char mzt[24][68];
  __shared__ float rt[20][68];

  int tid = threadIdx.x;
  int b = blockIdx.y, A0 = blockIdx.x * OWN;

  // phase 1: maze tile + qw2 + W_eff partials + beff partials
  for (int i = tid; i < 24 * 68; i += 256) {
    int mr = i / 68, mc = i % 68;
    int gy = A0 - 4 + mr, gx = mc - 2;
    unsigned char v = 3;
    if (gy >= 0 && gy < 64 && gx >= 0 && gx < 64)
      v = (unsigned char)maze[(b * 64 + gy) * 64 + gx];
    mzt[mr][mc] = v;
  }
  if (tid < 100) {
    int k = tid >> 2, j = tid & 3;
    qw2[k][j] = (v2f){q_w[(2 * j) * 25 + k], q_w[(2 * j + 1) * 25 + k]};
  }
  if (tid < 250) {
    int ik = tid % 50, chunk = tid / 50;
    int i = ik / 25, k = ik % 25;
    int c0 = chunk * 30;
    float s = 0.f;
    for (int c = c0; c < c0 + 30; ++c)
      s += r_w[c] * encode_w[c * 50 + i * 25 + k];
    wpart[tid] = s;
  }
  if (tid < 150) bpart[tid] = r_w[tid] * encode_b[tid];
  __syncthreads();
  // phase 2: reduce
  if (tid < 50) {
    float s = 0.f;
    for (int ch = 0; ch < 5; ++ch) s += wpart[ch * 50 + tid];
    weff[tid / 25][tid % 25] = s;
  }
  if (tid == 50) {
    float s = 0.f;
    for (int c = 0; c < 150; ++c) s += bpart[c];
    bsh = s;
  }
  __syncthreads();
  // phase 3: tap table T[val][k]
  if (tid < 100) {
    int val = tid / 25, k = tid % 25;
    float t = 0.f;
    if (val < 3) t = weff[0][k] * emb[val * 2] + weff[1][k] * emb[val * 2 + 1];
    Ts[val][k] = t;
  }
  __syncthreads();
  // phase 4: r tile rows [A0-2, A0+18) (zero outside image)
  // r(gy_r=A0-2+rr, gx_r=cc-2) taps maze(gy_r+ky-2, gx_r+kx-2)
  //   -> mzt row rr+ky, col (gx_r+kx-2)+2 = cc-2+kx
  for (int i = tid; i < 20 * 68; i += 256) {
    int rr = i / 68, cc = i % 68;
    int gy = A0 - 2 + rr, gx = cc - 2;
    float v = 0.f;
    if (gy >= 0 && gy < 64 && gx >= 0 && gx < 64) {
      v = bsh;
#pragma unroll
      for (int ky = 0; ky < 5; ++ky)
#pragma unroll
        for (int kx = 0; kx < 5; ++kx)
          v += Ts[mzt[rr + ky][cc - 2 + kx]][ky * 5 + kx];
    }
    rt[rr][cc] = v;
  }
  __syncthreads();
  // phase 5: q0 on owned 16 rows
  for (int i = tid; i < OWN * 64; i += 256) {
    int ly = i >> 6, gx = i & 63;
    int gy = A0 + ly;
    v2f acc[4];
#pragma unroll
    for (int j = 0; j < 4; ++j) acc[j] = (v2f){0.f, 0.f};
#pragma unroll
    for (int ky = 0; ky < 5; ++ky)
#pragma unroll
      for (int kx = 0; kx < 5; ++kx) {
        int k = ky * 5 + kx;
        float vv = rt[ly + ky][gx + kx];
        v2f vv2 = (v2f){vv, vv};
#pragma unroll
        for (int j = 0; j < 4; ++j) acc[j] += qw2[k][j] * vv2;
      }
    float* dst = q0g + ((size_t)(b * 4096 + gy * 64 + gx)) * NHAT;
    ((float4*)dst)[0] = make_float4(acc[0].x, acc[0].y, acc[1].x, acc[1].y);
    ((float4*)dst)[1] = make_float4(acc[2].x, acc[2].y, acc[3].x, acc[3].y);
  }
}

// =============== Kernel B: 10 fused VI steps + projection =================
// Block owns rows [a0, a0+16) of image b. Computes v_t on region
// [max(0,a0-2(10-t)), min(64, a0+16+2(10-t))) entirely in LDS; reads q0 from
// global each step (L2-resident). Step 10 projects directly to out.
__global__ __launch_bounds__(1024) void vi_kernel(
    const float* __restrict__ q0g, const float* __restrict__ w,
    const float* __restrict__ fc_w, float* __restrict__ out) {
  __shared__ float vbuf[2][64][68];  // lds_row = gy - a0 + 22, col = gx + 2
  __shared__ v2f wl2[25][4];
  __shared__ float fcs[4][NHAT];

  int tid = threadIdx.x;
  int b = blockIdx.y, a0 = blockIdx.x * OWN;
  int wave = tid >> 6, gx = tid & 63;

  if (tid < 100) {
    int k = tid >> 2, j = tid & 3;
    wl2[k][j] = (v2f){w[(2 * j) * 25 + k], w[(2 * j + 1) * 25 + k]};
  } else if (tid >= 128 && tid < 160) {
    int t = tid - 128;
    fcs[t >> 3][t & 7] = fc_w[t];
  }
  for (int i = tid; i < 2 * 64 * 68; i += 1024) ((float*)vbuf)[i] = 0.f;
  __syncthreads();

  const float* q0b = q0g + (size_t)b * 4096 * NHAT;
  int cur = 0;

  // v0 = max_c q0 on region [a0-20, a0+36) clipped
  {
    int s = max(0, a0 - 20), e = min(64, a0 + OWN + 20);
    int ng = (e - s + 3) >> 2;
    for (int g = wave; g < ng; g += 16) {
      int gy0 = s + g * 4;
#pragma unroll
      for (int j = 0; j < 4; ++j) {
        int gy = gy0 + j;
        if (gy < e) {
          const float4* p = (const float4*)(q0b + ((size_t)gy * 64 + gx) * NHAT);
          float4 f0 = p[0], f1 = p[1];
          float m = fmaxf(fmaxf(fmaxf(f0.x, f0.y), fmaxf(f0.z, f0.w)),
                          fmaxf(fmaxf(f1.x, f1.y), fmaxf(f1.z, f1.w)));
          vbuf[0][gy - a0 + 22][gx + 2] = m;
        }
      }
    }
  }
  __syncthreads();

  for (int t = 1; t <= 10; ++t) {
    int hh = 2 * (10 - t);
    int s = max(0, a0 - hh), e = min(64, a0 + OWN + hh);
    int ng = (e - s + 3) >> 2;
    for (int g = wave; g < ng; g += 16) {
      int gy0 = s + g * 4;
      // register v-patch: rows gy0-2 .. gy0+5, cols gx-2..gx+2
      float vp[8][5];
      int lr0 = gy0 - a0 + 20;
#pragma unroll
      for (int rr = 0; rr < 8; ++rr)
#pragma unroll
        for (int cc = 0; cc < 5; ++cc)
          vp[rr][cc] = vbuf[cur][lr0 + rr][gx + cc];
      // acc init from q0
      v2f acc[4][4];
#pragma unroll
      for (int px = 0; px < 4; ++px) {
        int gy = gy0 + px;
        if (gy < e) {
          const float4* p = (const float4*)(q0b + ((size_t)gy * 64 + gx) * NHAT);
          float4 f0 = p[0], f1 = p[1];
          acc[px][0] = (v2f){f0.x, f0.y};
          acc[px][1] = (v2f){f0.z, f0.w};
          acc[px][2] = (v2f){f1.x, f1.y};
          acc[px][3] = (v2f){f1.z, f1.w};
        } else {
#pragma unroll
          for (int j = 0; j < 4; ++j) acc[px][j] = (v2f){0.f, 0.f};
        }
      }
      // conv: 25 taps x 8 ch (4 v2f) x 4 px
#pragma unroll
      for (int ky = 0; ky < 5; ++ky)
#pragma unroll
        for (int kx = 0; kx < 5; ++kx) {
          int k = ky * 5 + kx;
          v2f w0 = wl2[k][0], w1 = wl2[k][1], w2 = wl2[k][2], w3 = wl2[k][3];
#pragma unroll
          for (int px = 0; px < 4; ++px) {
            float vv = vp[px + ky][kx];
            v2f vv2 = (v2f){vv, vv};
            acc[px][0] += w0 * vv2;
            acc[px][1] += w1 * vv2;
            acc[px][2] += w2 * vv2;
            acc[px][3] += w3 * vv2;
          }
        }
      if (t < 10) {
#pragma unroll
        for (int px = 0; px < 4; ++px) {
          int gy = gy0 + px;
          if (gy < e) {
            float m = fmaxf(
                fmaxf(fmaxf(acc[px][0].x, acc[px][0].y),
                      fmaxf(acc[px][1].x, acc[px][1].y)),
                fmaxf(fmaxf(acc[px][2].x, acc[px][2].y),
                      fmaxf(acc[px][3].x, acc[px][3].y)));
            vbuf[cur ^ 1][gy - a0 + 22][gx + 2] = m;
          }
        }
      } else {
#pragma unroll
        for (int px = 0; px < 4; ++px) {
          int gy = gy0 + px;
          if (gy < e) {
            float q[8] = {acc[px][0].x, acc[px][0].y, acc[px][1].x, acc[px][1].y,
                          acc[px][2].x, acc[px][2].y, acc[px][3].x, acc[px][3].y};
            float4 o;
            float* op = &o.x;
#pragma unroll
            for (int a = 0; a < 4; ++a) {
              float ssum = 0.f;
#pragma unroll
              for (int c = 0; c < 8; ++c) ssum += fcs[a][c] * q[c];
              op[a] = ssum;
            }
            *(float4*)&out[((size_t)((b * 64 + gy) * 64 + gx)) * 4] = o;
          }
        }
      }
    }
    cur ^= 1;
    if (t < 10) __syncthreads();
  }
}

extern "C" void kernel_launch(void* const* d_in, const int* in_sizes, int n_in,
                              void* d_out, int out_size, void* d_ws, size_t ws_size,
                              hipStream_t stream) {
  const int* maze = (const int*)d_in[0];
  const float* emb = (const float*)d_in[1];
  const float* encode_w = (const float*)d_in[2];
  const float* encode_b = (const float*)d_in[3];
  const float* r_w = (const float*)d_in[4];
  const float* q_w = (const float*)d_in[5];
  const float* w = (const float*)d_in[6];
  const float* fc_w = (const float*)d_in[7];
  float* out = (float*)d_out;

  float* q0 = (float*)d_ws;  // 64*64*64*8 floats = 8 MB

  dim3 grid(4, 64);  // 4 quarters x 64 images
  rq_kernel<<<grid, 256, 0, stream>>>(maze, emb, encode_w, encode_b, r_w, q_w, q0);
  vi_kernel<<<grid, 1024, 0, stream>>>(q0, w, fc_w, out);
}

// Round 5
// 320.009 us; speedup vs baseline: 2.2498x; 2.2498x over previous
//
#include <hip/hip_runtime.h>
#include <hip/hip_bf16.h>

// Nav_64939905516231 (VIN value iteration), MI355X gfx950.
// B=64,H=W=64,dim_h=150,n_hat=8,n_act=4,K=10. fp32 in/out, maze int32.
// Collapses: r = conv5x5(m,W_eff)+b_eff (150ch folded); q_t = q0 + conv5x5(v,w).
// 2 kernels: A = prep+r+q0 (per image-quarter); B = 10 fused steps + projection,
// redundant halo compute (block owns 16 rows, computes shrinking region).
// R4 lesson: 1024-thr block forced VGPR=64 -> ~2.1 GB scratch-spill traffic,
// 632 us. R5: 256-thr blocks, __launch_bounds__(256,2) (VGPR cap 256, no
// spill); waves stride the row-groups.

#define NHAT 8
#define DIMH 150
#define OWN 16

typedef float v2f __attribute__((ext_vector_type(2)));

// =============== Kernel A: prep + r + q0 =================
__global__ __launch_bounds__(256) void rq_kernel(
    const int* __restrict__ maze, const float* __restrict__ emb,
    const float* __restrict__ encode_w, const float* __restrict__ encode_b,
    const float* __restrict__ r_w, const float* __restrict__ q_w,
    float* __restrict__ q0g) {
  __shared__ float wpart[250];     // 5 chunks x 50 (i,k)
  __shared__ float bpart[152];
  __shared__ float weff[2][25];
  __shared__ float bsh;
  __shared__ float Ts[4][25];
  __shared__ v2f qw2[25][4];
  __shared__ unsigned char mzt[24][68];
  __shared__ float rt[20][68];

  int tid = threadIdx.x;
  int b = blockIdx.y, A0 = blockIdx.x * OWN;

  // phase 1: maze tile + qw2 + W_eff partials + beff partials
  for (int i = tid; i < 24 * 68; i += 256) {
    int mr = i / 68, mc = i % 68;
    int gy = A0 - 4 + mr, gx = mc - 2;
    unsigned char v = 3;
    if (gy >= 0 && gy < 64 && gx >= 0 && gx < 64)
      v = (unsigned char)maze[(b * 64 + gy) * 64 + gx];
    mzt[mr][mc] = v;
  }
  if (tid < 100) {
    int k = tid >> 2, j = tid & 3;
    qw2[k][j] = (v2f){q_w[(2 * j) * 25 + k], q_w[(2 * j + 1) * 25 + k]};
  }
  if (tid < 250) {
    int ik = tid % 50, chunk = tid / 50;
    int i = ik / 25, k = ik % 25;
    int c0 = chunk * 30;
    float s = 0.f;
    for (int c = c0; c < c0 + 30; ++c)
      s += r_w[c] * encode_w[c * 50 + i * 25 + k];
    wpart[tid] = s;
  }
  if (tid < 150) bpart[tid] = r_w[tid] * encode_b[tid];
  __syncthreads();
  // phase 2: reduce
  if (tid < 50) {
    float s = 0.f;
    for (int ch = 0; ch < 5; ++ch) s += wpart[ch * 50 + tid];
    weff[tid / 25][tid % 25] = s;
  }
  if (tid == 50) {
    float s = 0.f;
    for (int c = 0; c < 150; ++c) s += bpart[c];
    bsh = s;
  }
  __syncthreads();
  // phase 3: tap table T[val][k]
  if (tid < 100) {
    int val = tid / 25, k = tid % 25;
    float t = 0.f;
    if (val < 3) t = weff[0][k] * emb[val * 2] + weff[1][k] * emb[val * 2 + 1];
    Ts[val][k] = t;
  }
  __syncthreads();
  // phase 4: r tile rows [A0-2, A0+18) (zero outside image)
  // r(gy_r=A0-2+rr, gx_r=cc-2) taps maze(gy_r+ky-2, gx_r+kx-2)
  //   -> mzt row rr+ky, col cc-2+kx
  for (int i = tid; i < 20 * 68; i += 256) {
    int rr = i / 68, cc = i % 68;
    int gy = A0 - 2 + rr, gx = cc - 2;
    float v = 0.f;
    if (gy >= 0 && gy < 64 && gx >= 0 && gx < 64) {
      v = bsh;
#pragma unroll
      for (int ky = 0; ky < 5; ++ky)
#pragma unroll
        for (int kx = 0; kx < 5; ++kx)
          v += Ts[mzt[rr + ky][cc - 2 + kx]][ky * 5 + kx];
    }
    rt[rr][cc] = v;
  }
  __syncthreads();
  // phase 5: q0 on owned 16 rows
  for (int i = tid; i < OWN * 64; i += 256) {
    int ly = i >> 6, gx = i & 63;
    int gy = A0 + ly;
    v2f acc[4];
#pragma unroll
    for (int j = 0; j < 4; ++j) acc[j] = (v2f){0.f, 0.f};
#pragma unroll
    for (int ky = 0; ky < 5; ++ky)
#pragma unroll
      for (int kx = 0; kx < 5; ++kx) {
        int k = ky * 5 + kx;
        float vv = rt[ly + ky][gx + kx];
        v2f vv2 = (v2f){vv, vv};
#pragma unroll
        for (int j = 0; j < 4; ++j) acc[j] += qw2[k][j] * vv2;
      }
    float* dst = q0g + ((size_t)(b * 4096 + gy * 64 + gx)) * NHAT;
    ((float4*)dst)[0] = make_float4(acc[0].x, acc[0].y, acc[1].x, acc[1].y);
    ((float4*)dst)[1] = make_float4(acc[2].x, acc[2].y, acc[3].x, acc[3].y);
  }
}

// =============== Kernel B: 10 fused VI steps + projection =================
// Block (256 thr, 4 waves) owns rows [a0, a0+16) of image b. Computes v_t on
// [max(0,a0-2(10-t)), min(64, a0+16+2(10-t))) entirely in LDS; q0 read from
// global each step (L2-resident). Step 10 projects directly to out.
// __launch_bounds__(256,2): VGPR cap 256 so vp[40]+acc[32] stay in registers.
__global__ __launch_bounds__(256, 2) void vi_kernel(
    const float* __restrict__ q0g, const float* __restrict__ w,
    const float* __restrict__ fc_w, float* __restrict__ out) {
  __shared__ float vbuf[2][64][68];  // lds_row = gy - a0 + 22, col = gx + 2
  __shared__ v2f wl2[25][4];
  __shared__ float fcs[4][NHAT];

  int tid = threadIdx.x;
  int b = blockIdx.y, a0 = blockIdx.x * OWN;
  int wave = tid >> 6, gx = tid & 63;

  if (tid < 100) {
    int k = tid >> 2, j = tid & 3;
    wl2[k][j] = (v2f){w[(2 * j) * 25 + k], w[(2 * j + 1) * 25 + k]};
  } else if (tid >= 128 && tid < 160) {
    int t = tid - 128;
    fcs[t >> 3][t & 7] = fc_w[t];
  }
  for (int i = tid; i < 2 * 64 * 68; i += 256) ((float*)vbuf)[i] = 0.f;
  __syncthreads();

  const float* q0b = q0g + (size_t)b * 4096 * NHAT;
  int cur = 0;

  // v0 = max_c q0 on region [a0-20, a0+36) clipped
  {
    int s = max(0, a0 - 20), e = min(64, a0 + OWN + 20);
    int ng = (e - s + 3) >> 2;
    for (int g = wave; g < ng; g += 4) {
      int gy0 = s + g * 4;
#pragma unroll
      for (int j = 0; j < 4; ++j) {
        int gy = gy0 + j;
        if (gy < e) {
          const float4* p = (const float4*)(q0b + ((size_t)gy * 64 + gx) * NHAT);
          float4 f0 = p[0], f1 = p[1];
          float m = fmaxf(fmaxf(fmaxf(f0.x, f0.y), fmaxf(f0.z, f0.w)),
                          fmaxf(fmaxf(f1.x, f1.y), fmaxf(f1.z, f1.w)));
          vbuf[0][gy - a0 + 22][gx + 2] = m;
        }
      }
    }
  }
  __syncthreads();

  for (int t = 1; t <= 10; ++t) {
    int hh = 2 * (10 - t);
    int s = max(0, a0 - hh), e = min(64, a0 + OWN + hh);
    int ng = (e - s + 3) >> 2;
    for (int g = wave; g < ng; g += 4) {
      int gy0 = s + g * 4;
      // register v-patch: rows gy0-2 .. gy0+5, cols gx-2..gx+2
      float vp[8][5];
      int lr0 = gy0 - a0 + 20;
#pragma unroll
      for (int rr = 0; rr < 8; ++rr)
#pragma unroll
        for (int cc = 0; cc < 5; ++cc)
          vp[rr][cc] = vbuf[cur][lr0 + rr][gx + cc];
      // acc init from q0
      v2f acc[4][4];
#pragma unroll
      for (int px = 0; px < 4; ++px) {
        int gy = gy0 + px;
        if (gy < e) {
          const float4* p = (const float4*)(q0b + ((size_t)gy * 64 + gx) * NHAT);
          float4 f0 = p[0], f1 = p[1];
          acc[px][0] = (v2f){f0.x, f0.y};
          acc[px][1] = (v2f){f0.z, f0.w};
          acc[px][2] = (v2f){f1.x, f1.y};
          acc[px][3] = (v2f){f1.z, f1.w};
        } else {
#pragma unroll
          for (int j = 0; j < 4; ++j) acc[px][j] = (v2f){0.f, 0.f};
        }
      }
      // conv: 25 taps x 8 ch (4 v2f) x 4 px
#pragma unroll
      for (int ky = 0; ky < 5; ++ky)
#pragma unroll
        for (int kx = 0; kx < 5; ++kx) {
          int k = ky * 5 + kx;
          v2f w0 = wl2[k][0], w1 = wl2[k][1], w2 = wl2[k][2], w3 = wl2[k][3];
#pragma unroll
          for (int px = 0; px < 4; ++px) {
            float vv = vp[px + ky][kx];
            v2f vv2 = (v2f){vv, vv};
            acc[px][0] += w0 * vv2;
            acc[px][1] += w1 * vv2;
            acc[px][2] += w2 * vv2;
            acc[px][3] += w3 * vv2;
          }
        }
      if (t < 10) {
#pragma unroll
        for (int px = 0; px < 4; ++px) {
          int gy = gy0 + px;
          if (gy < e) {
            float m = fmaxf(
                fmaxf(fmaxf(acc[px][0].x, acc[px][0].y),
                      fmaxf(acc[px][1].x, acc[px][1].y)),
                fmaxf(fmaxf(acc[px][2].x, acc[px][2].y),
                      fmaxf(acc[px][3].x, acc[px][3].y)));
            vbuf[cur ^ 1][gy - a0 + 22][gx + 2] = m;
          }
        }
      } else {
#pragma unroll
        for (int px = 0; px < 4; ++px) {
          int gy = gy0 + px;
          if (gy < e) {
            float q[8] = {acc[px][0].x, acc[px][0].y, acc[px][1].x, acc[px][1].y,
                          acc[px][2].x, acc[px][2].y, acc[px][3].x, acc[px][3].y};
            float4 o;
            float* op = &o.x;
#pragma unroll
            for (int a = 0; a < 4; ++a) {
              float ssum = 0.f;
#pragma unroll
              for (int c = 0; c < 8; ++c) ssum += fcs[a][c] * q[c];
              op[a] = ssum;
            }
            *(float4*)&out[((size_t)((b * 64 + gy) * 64 + gx)) * 4] = o;
          }
        }
      }
    }
    cur ^= 1;
    if (t < 10) __syncthreads();
  }
}

extern "C" void kernel_launch(void* const* d_in, const int* in_sizes, int n_in,
                              void* d_out, int out_size, void* d_ws, size_t ws_size,
                              hipStream_t stream) {
  const int* maze = (const int*)d_in[0];
  const float* emb = (const float*)d_in[1];
  const float* encode_w = (const float*)d_in[2];
  const float* encode_b = (const float*)d_in[3];
  const float* r_w = (const float*)d_in[4];
  const float* q_w = (const float*)d_in[5];
  const float* w = (const float*)d_in[6];
  const float* fc_w = (const float*)d_in[7];
  float* out = (float*)d_out;

  float* q0 = (float*)d_ws;  // 64*64*64*8 floats = 8 MB

  dim3 grid(4, 64);  // 4 quarters x 64 images
  rq_kernel<<<grid, 256, 0, stream>>>(maze, emb, encode_w, encode_b, r_w, q_w, q0);
  vi_kernel<<<grid, 256, 0, stream>>>(q0, w, fc_w, out);
}

// Round 6
// 141.367 us; speedup vs baseline: 5.0927x; 2.2637x over previous
//
#include <hip/hip_runtime.h>
#include <hip/hip_bf16.h>

// Nav_64939905516231 (VIN value iteration), MI355X gfx950.
// B=64,H=W=64,dim_h=150,n_hat=8,n_act=4,K=10. fp32 in/out, maze int32.
// Collapses: r = conv5x5(m,W_eff)+b_eff (150ch folded); q_t = q0 + conv5x5(v,w).
// 2 kernels: A = prep+r+q0; B = 10 fused steps + projection, redundant halo
// compute (block owns 16 rows, computes shrinking region).
// R4: 1024-thr -> VGPR 64, 2.1 GB spill, 632us. R5: 256-thr 4px/lane -> VGPR
// 128, still ~0.6 GB spill, 247us. R6: 1 px/lane (wave = one row), 512-thr
// blocks -> ~50 live floats/lane, no spill.

#define NHAT 8
#define DIMH 150
#define OWN 16

typedef float v2f __attribute__((ext_vector_type(2)));

// =============== Kernel A: prep + r + q0 =================
__global__ __launch_bounds__(256) void rq_kernel(
    const int* __restrict__ maze, const float* __restrict__ emb,
    const float* __restrict__ encode_w, const float* __restrict__ encode_b,
    const float* __restrict__ r_w, const float* __restrict__ q_w,
    float* __restrict__ q0g) {
  __shared__ float wpart[250];     // 5 chunks x 50 (i,k)
  __shared__ float bpart[152];
  __shared__ float weff[2][25];
  __shared__ float bsh;
  __shared__ float Ts[4][25];
  __shared__ v2f qw2[25][4];
  __shared__ unsigned char mzt[24][68];
  __shared__ float rt[20][68];

  int tid = threadIdx.x;
  int b = blockIdx.y, A0 = blockIdx.x * OWN;

  for (int i = tid; i < 24 * 68; i += 256) {
    int mr = i / 68, mc = i % 68;
    int gy = A0 - 4 + mr, gx = mc - 2;
    unsigned char v = 3;
    if (gy >= 0 && gy < 64 && gx >= 0 && gx < 64)
      v = (unsigned char)maze[(b * 64 + gy) * 64 + gx];
    mzt[mr][mc] = v;
  }
  if (tid < 100) {
    int k = tid >> 2, j = tid & 3;
    qw2[k][j] = (v2f){q_w[(2 * j) * 25 + k], q_w[(2 * j + 1) * 25 + k]};
  }
  if (tid < 250) {
    int ik = tid % 50, chunk = tid / 50;
    int i = ik / 25, k = ik % 25;
    int c0 = chunk * 30;
    float s = 0.f;
    for (int c = c0; c < c0 + 30; ++c)
      s += r_w[c] * encode_w[c * 50 + i * 25 + k];
    wpart[tid] = s;
  }
  if (tid < 150) bpart[tid] = r_w[tid] * encode_b[tid];
  __syncthreads();
  if (tid < 50) {
    float s = 0.f;
    for (int ch = 0; ch < 5; ++ch) s += wpart[ch * 50 + tid];
    weff[tid / 25][tid % 25] = s;
  }
  if (tid == 50) {
    float s = 0.f;
    for (int c = 0; c < 150; ++c) s += bpart[c];
    bsh = s;
  }
  __syncthreads();
  if (tid < 100) {
    int val = tid / 25, k = tid % 25;
    float t = 0.f;
    if (val < 3) t = weff[0][k] * emb[val * 2] + weff[1][k] * emb[val * 2 + 1];
    Ts[val][k] = t;
  }
  __syncthreads();
  // r tile rows [A0-2, A0+18): r(A0-2+rr, cc-2) taps mzt[rr+ky][cc-2+kx]
  for (int i = tid; i < 20 * 68; i += 256) {
    int rr = i / 68, cc = i % 68;
    int gy = A0 - 2 + rr, gx = cc - 2;
    float v = 0.f;
    if (gy >= 0 && gy < 64 && gx >= 0 && gx < 64) {
      v = bsh;
#pragma unroll
      for (int ky = 0; ky < 5; ++ky)
#pragma unroll
        for (int kx = 0; kx < 5; ++kx)
          v += Ts[mzt[rr + ky][cc - 2 + kx]][ky * 5 + kx];
    }
    rt[rr][cc] = v;
  }
  __syncthreads();
  for (int i = tid; i < OWN * 64; i += 256) {
    int ly = i >> 6, gx = i & 63;
    int gy = A0 + ly;
    v2f acc[4];
#pragma unroll
    for (int j = 0; j < 4; ++j) acc[j] = (v2f){0.f, 0.f};
#pragma unroll
    for (int ky = 0; ky < 5; ++ky)
#pragma unroll
      for (int kx = 0; kx < 5; ++kx) {
        int k = ky * 5 + kx;
        float vv = rt[ly + ky][gx + kx];
        v2f vv2 = (v2f){vv, vv};
#pragma unroll
        for (int j = 0; j < 4; ++j) acc[j] += qw2[k][j] * vv2;
      }
    float* dst = q0g + ((size_t)(b * 4096 + gy * 64 + gx)) * NHAT;
    ((float4*)dst)[0] = make_float4(acc[0].x, acc[0].y, acc[1].x, acc[1].y);
    ((float4*)dst)[1] = make_float4(acc[2].x, acc[2].y, acc[3].x, acc[3].y);
  }
}

// =============== Kernel B: 10 fused VI steps + projection =================
// Block (512 thr = 8 waves) owns rows [a0, a0+16) of image b. Wave = one
// 64-px row; lane = one pixel. v_t computed on the shrinking region
// [max(0,a0-2(10-t)), min(64, a0+16+2(10-t))) in LDS; q0 from global (L2).
__global__ __launch_bounds__(512, 2) void vi_kernel(
    const float* __restrict__ q0g, const float* __restrict__ w,
    const float* __restrict__ fc_w, float* __restrict__ out) {
  __shared__ float vbuf[2][64][68];  // lds_row = gy - a0 + 22, col = gx + 2
  __shared__ v2f wl2[25][4];
  __shared__ float fcs[4][NHAT];

  int tid = threadIdx.x;
  int b = blockIdx.y, a0 = blockIdx.x * OWN;
  int wave = tid >> 6, gx = tid & 63;

  if (tid < 100) {
    int k = tid >> 2, j = tid & 3;
    wl2[k][j] = (v2f){w[(2 * j) * 25 + k], w[(2 * j + 1) * 25 + k]};
  } else if (tid >= 128 && tid < 160) {
    int t = tid - 128;
    fcs[t >> 3][t & 7] = fc_w[t];
  }
  for (int i = tid; i < 2 * 64 * 68; i += 512) ((float*)vbuf)[i] = 0.f;
  __syncthreads();

  const float* q0b = q0g + (size_t)b * 4096 * NHAT;
  int cur = 0;

  // v0 = max_c q0 on [a0-20, a0+36) clipped
  {
    int s = max(0, a0 - 20), e = min(64, a0 + OWN + 20);
    for (int r = s + wave; r < e; r += 8) {
      const float4* p = (const float4*)(q0b + ((size_t)r * 64 + gx) * NHAT);
      float4 f0 = p[0], f1 = p[1];
      float m = fmaxf(fmaxf(fmaxf(f0.x, f0.y), fmaxf(f0.z, f0.w)),
                      fmaxf(fmaxf(f1.x, f1.y), fmaxf(f1.z, f1.w)));
      vbuf[0][r - a0 + 22][gx + 2] = m;
    }
  }
  __syncthreads();

  for (int t = 1; t <= 10; ++t) {
    int hh = 2 * (10 - t);
    int s = max(0, a0 - hh), e = min(64, a0 + OWN + hh);
    for (int r = s + wave; r < e; r += 8) {
      int lr = r - a0 + 22;
      // issue global q0 first (latency overlap), then LDS patch
      const float4* p = (const float4*)(q0b + ((size_t)r * 64 + gx) * NHAT);
      float4 f0 = p[0], f1 = p[1];
      float vp[5][5];
#pragma unroll
      for (int dr = 0; dr < 5; ++dr)
#pragma unroll
        for (int dc = 0; dc < 5; ++dc)
          vp[dr][dc] = vbuf[cur][lr - 2 + dr][gx + dc];
      v2f a0v = (v2f){f0.x, f0.y}, a1v = (v2f){f0.z, f0.w};
      v2f a2v = (v2f){f1.x, f1.y}, a3v = (v2f){f1.z, f1.w};
#pragma unroll
      for (int ky = 0; ky < 5; ++ky)
#pragma unroll
        for (int kx = 0; kx < 5; ++kx) {
          int k = ky * 5 + kx;
          float vv = vp[ky][kx];
          v2f vv2 = (v2f){vv, vv};
          a0v += wl2[k][0] * vv2;
          a1v += wl2[k][1] * vv2;
          a2v += wl2[k][2] * vv2;
          a3v += wl2[k][3] * vv2;
        }
      if (t < 10) {
        float m = fmaxf(fmaxf(fmaxf(a0v.x, a0v.y), fmaxf(a1v.x, a1v.y)),
                        fmaxf(fmaxf(a2v.x, a2v.y), fmaxf(a3v.x, a3v.y)));
        vbuf[cur ^ 1][lr][gx + 2] = m;
      } else {
        float4 o;
        float* op = &o.x;
#pragma unroll
        for (int a = 0; a < 4; ++a) {
          op[a] = fcs[a][0] * a0v.x + fcs[a][1] * a0v.y + fcs[a][2] * a1v.x +
                  fcs[a][3] * a1v.y + fcs[a][4] * a2v.x + fcs[a][5] * a2v.y +
                  fcs[a][6] * a3v.x + fcs[a][7] * a3v.y;
        }
        *(float4*)&out[((size_t)((b * 64 + r) * 64 + gx)) * 4] = o;
      }
    }
    cur ^= 1;
    if (t < 10) __syncthreads();
  }
}

extern "C" void kernel_launch(void* const* d_in, const int* in_sizes, int n_in,
                              void* d_out, int out_size, void* d_ws, size_t ws_size,
                              hipStream_t stream) {
  const int* maze = (const int*)d_in[0];
  const float* emb = (const float*)d_in[1];
  const float* encode_w = (const float*)d_in[2];
  const float* encode_b = (const float*)d_in[3];
  const float* r_w = (const float*)d_in[4];
  const float* q_w = (const float*)d_in[5];
  const float* w = (const float*)d_in[6];
  const float* fc_w = (const float*)d_in[7];
  float* out = (float*)d_out;

  float* q0 = (float*)d_ws;  // 64*64*64*8 floats = 8 MB

  dim3 grid(4, 64);  // 4 quarters x 64 images
  rq_kernel<<<grid, 256, 0, stream>>>(maze, emb, encode_w, encode_b, r_w, q_w, q0);
  vi_kernel<<<grid, 512, 0, stream>>>(q0, w, fc_w, out);
}

// Round 7
// 129.794 us; speedup vs baseline: 5.5468x; 1.0892x over previous
//
#include <hip/hip_runtime.h>
#include <hip/hip_bf16.h>

// Nav_64939905516231 (VIN value iteration), MI355X gfx950.
// B=64,H=W=64,dim_h=150,n_hat=8,n_act=4,K=10. fp32 in/out, maze int32.
// Collapses: r = conv5x5(m,W_eff)+b_eff (150ch folded); q_t = q0 + conv5x5(v,w).
// 2 kernels: A = prep+r+q0; B = 10 fused steps + projection, redundant halo
// compute (block owns 16 rows, computes shrinking region).
// Spill ladder: R4 1024-thr VGPR64 -> 2.1GB spill, 632us. R5 256-thr 4px/lane
// VGPR128 -> 0.6GB spill, 247us. R6 1px/lane but vp[25] reg-patch -> still
// 130MB spill, 66us. R7: drop the vp patch (each tap used ONCE) -- read LDS
// directly in the FMA loop; live set ~25 floats, no spill at any VGPR target.

#define NHAT 8
#define DIMH 150
#define OWN 16

typedef float v2f __attribute__((ext_vector_type(2)));

// =============== Kernel A: prep + r + q0 =================
__global__ __launch_bounds__(256) void rq_kernel(
    const int* __restrict__ maze, const float* __restrict__ emb,
    const float* __restrict__ encode_w, const float* __restrict__ encode_b,
    const float* __restrict__ r_w, const float* __restrict__ q_w,
    float* __restrict__ q0g) {
  __shared__ float wpart[250];     // 5 chunks x 50 (i,k)
  __shared__ float bpart[152];
  __shared__ float weff[2][25];
  __shared__ float bsh;
  __shared__ float Ts[4][25];
  __shared__ v2f qw2[25][4];
  __shared__ unsigned char mzt[24][68];
  __shared__ float rt[20][68];

  int tid = threadIdx.x;
  int b = blockIdx.y, A0 = blockIdx.x * OWN;

  for (int i = tid; i < 24 * 68; i += 256) {
    int mr = i / 68, mc = i % 68;
    int gy = A0 - 4 + mr, gx = mc - 2;
    unsigned char v = 3;
    if (gy >= 0 && gy < 64 && gx >= 0 && gx < 64)
      v = (unsigned char)maze[(b * 64 + gy) * 64 + gx];
    mzt[mr][mc] = v;
  }
  if (tid < 100) {
    int k = tid >> 2, j = tid & 3;
    qw2[k][j] = (v2f){q_w[(2 * j) * 25 + k], q_w[(2 * j + 1) * 25 + k]};
  }
  if (tid < 250) {
    int ik = tid % 50, chunk = tid / 50;
    int i = ik / 25, k = ik % 25;
    int c0 = chunk * 30;
    float s = 0.f;
    for (int c = c0; c < c0 + 30; ++c)
      s += r_w[c] * encode_w[c * 50 + i * 25 + k];
    wpart[tid] = s;
  }
  if (tid < 150) bpart[tid] = r_w[tid] * encode_b[tid];
  __syncthreads();
  if (tid < 50) {
    float s = 0.f;
    for (int ch = 0; ch < 5; ++ch) s += wpart[ch * 50 + tid];
    weff[tid / 25][tid % 25] = s;
  }
  if (tid == 50) {
    float s = 0.f;
    for (int c = 0; c < 150; ++c) s += bpart[c];
    bsh = s;
  }
  __syncthreads();
  if (tid < 100) {
    int val = tid / 25, k = tid % 25;
    float t = 0.f;
    if (val < 3) t = weff[0][k] * emb[val * 2] + weff[1][k] * emb[val * 2 + 1];
    Ts[val][k] = t;
  }
  __syncthreads();
  // r tile rows [A0-2, A0+18): r(A0-2+rr, cc-2) taps mzt[rr+ky][cc-2+kx]
  for (int i = tid; i < 20 * 68; i += 256) {
    int rr = i / 68, cc = i % 68;
    int gy = A0 - 2 + rr, gx = cc - 2;
    float v = 0.f;
    if (gy >= 0 && gy < 64 && gx >= 0 && gx < 64) {
      v = bsh;
#pragma unroll
      for (int ky = 0; ky < 5; ++ky)
#pragma unroll
        for (int kx = 0; kx < 5; ++kx)
          v += Ts[mzt[rr + ky][cc - 2 + kx]][ky * 5 + kx];
    }
    rt[rr][cc] = v;
  }
  __syncthreads();
  for (int i = tid; i < OWN * 64; i += 256) {
    int ly = i >> 6, gx = i & 63;
    int gy = A0 + ly;
    v2f acc[4];
#pragma unroll
    for (int j = 0; j < 4; ++j) acc[j] = (v2f){0.f, 0.f};
#pragma unroll
    for (int ky = 0; ky < 5; ++ky)
#pragma unroll
      for (int kx = 0; kx < 5; ++kx) {
        int k = ky * 5 + kx;
        float vv = rt[ly + ky][gx + kx];
        v2f vv2 = (v2f){vv, vv};
#pragma unroll
        for (int j = 0; j < 4; ++j) acc[j] += qw2[k][j] * vv2;
      }
    float* dst = q0g + ((size_t)(b * 4096 + gy * 64 + gx)) * NHAT;
    ((float4*)dst)[0] = make_float4(acc[0].x, acc[0].y, acc[1].x, acc[1].y);
    ((float4*)dst)[1] = make_float4(acc[2].x, acc[2].y, acc[3].x, acc[3].y);
  }
}

// =============== Kernel B: 10 fused VI steps + projection =================
// Block (512 thr = 8 waves) owns rows [a0, a0+16) of image b. Wave = one
// 64-px row; lane = one pixel. v_t computed on the shrinking region
// [max(0,a0-2(10-t)), min(64, a0+16+2(10-t))) in LDS; q0 from global (L2).
// Taps read straight from LDS inside the FMA loop (no register patch).
__global__ __launch_bounds__(512, 2) void vi_kernel(
    const float* __restrict__ q0g, const float* __restrict__ w,
    const float* __restrict__ fc_w, float* __restrict__ out) {
  __shared__ float vbuf[2][64][68];  // lds_row = gy - a0 + 22, col = gx + 2
  __shared__ v2f wl2[25][4];
  __shared__ float fcs[4][NHAT];

  int tid = threadIdx.x;
  int b = blockIdx.y, a0 = blockIdx.x * OWN;
  int wave = tid >> 6, gx = tid & 63;

  if (tid < 100) {
    int k = tid >> 2, j = tid & 3;
    wl2[k][j] = (v2f){w[(2 * j) * 25 + k], w[(2 * j + 1) * 25 + k]};
  } else if (tid >= 128 && tid < 160) {
    int t = tid - 128;
    fcs[t >> 3][t & 7] = fc_w[t];
  }
  for (int i = tid; i < 2 * 64 * 68; i += 512) ((float*)vbuf)[i] = 0.f;
  __syncthreads();

  const float* q0b = q0g + (size_t)b * 4096 * NHAT;
  int cur = 0;

  // v0 = max_c q0 on [a0-20, a0+36) clipped
  {
    int s = max(0, a0 - 20), e = min(64, a0 + OWN + 20);
    for (int r = s + wave; r < e; r += 8) {
      const float4* p = (const float4*)(q0b + ((size_t)r * 64 + gx) * NHAT);
      float4 f0 = p[0], f1 = p[1];
      float m = fmaxf(fmaxf(fmaxf(f0.x, f0.y), fmaxf(f0.z, f0.w)),
                      fmaxf(fmaxf(f1.x, f1.y), fmaxf(f1.z, f1.w)));
      vbuf[0][r - a0 + 22][gx + 2] = m;
    }
  }
  __syncthreads();

  for (int t = 1; t <= 10; ++t) {
    int hh = 2 * (10 - t);
    int s = max(0, a0 - hh), e = min(64, a0 + OWN + hh);
    for (int r = s + wave; r < e; r += 8) {
      int lr = r - a0 + 22;
      // issue global q0 first (latency overlap)
      const float4* p = (const float4*)(q0b + ((size_t)r * 64 + gx) * NHAT);
      float4 f0 = p[0], f1 = p[1];
      v2f a0v = (v2f){f0.x, f0.y}, a1v = (v2f){f0.z, f0.w};
      v2f a2v = (v2f){f1.x, f1.y}, a3v = (v2f){f1.z, f1.w};
      // conv taps straight from LDS (each value used exactly once)
#pragma unroll
      for (int ky = 0; ky < 5; ++ky) {
        const float* row = &vbuf[cur][lr - 2 + ky][gx];
#pragma unroll
        for (int kx = 0; kx < 5; ++kx) {
          int k = ky * 5 + kx;
          float vv = row[kx];
          v2f vv2 = (v2f){vv, vv};
          a0v += wl2[k][0] * vv2;
          a1v += wl2[k][1] * vv2;
          a2v += wl2[k][2] * vv2;
          a3v += wl2[k][3] * vv2;
        }
      }
      if (t < 10) {
        float m = fmaxf(fmaxf(fmaxf(a0v.x, a0v.y), fmaxf(a1v.x, a1v.y)),
                        fmaxf(fmaxf(a2v.x, a2v.y), fmaxf(a3v.x, a3v.y)));
        vbuf[cur ^ 1][lr][gx + 2] = m;
      } else {
        float4 o;
        float* op = &o.x;
#pragma unroll
        for (int a = 0; a < 4; ++a) {
          op[a] = fcs[a][0] * a0v.x + fcs[a][1] * a0v.y + fcs[a][2] * a1v.x +
                  fcs[a][3] * a1v.y + fcs[a][4] * a2v.x + fcs[a][5] * a2v.y +
                  fcs[a][6] * a3v.x + fcs[a][7] * a3v.y;
        }
        *(float4*)&out[((size_t)((b * 64 + r) * 64 + gx)) * 4] = o;
      }
    }
    cur ^= 1;
    if (t < 10) __syncthreads();
  }
}

extern "C" void kernel_launch(void* const* d_in, const int* in_sizes, int n_in,
                              void* d_out, int out_size, void* d_ws, size_t ws_size,
                              hipStream_t stream) {
  const int* maze = (const int*)d_in[0];
  const float* emb = (const float*)d_in[1];
  const float* encode_w = (const float*)d_in[2];
  const float* encode_b = (const float*)d_in[3];
  const float* r_w = (const float*)d_in[4];
  const float* q_w = (const float*)d_in[5];
  const float* w = (const float*)d_in[6];
  const float* fc_w = (const float*)d_in[7];
  float* out = (float*)d_out;

  float* q0 = (float*)d_ws;  // 64*64*64*8 floats = 8 MB

  dim3 grid(4, 64);  // 4 quarters x 64 images
  rq_kernel<<<grid, 256, 0, stream>>>(maze, emb, encode_w, encode_b, r_w, q_w, q0);
  vi_kernel<<<grid, 512, 0, stream>>>(q0, w, fc_w, out);
}